// Round 1
// baseline (449.962 us; speedup 1.0000x reference)
//
#include <hip/hip_runtime.h>

// 16-bit ripple-carry adder over BATCH rows.
// Inputs are float32 in {0,1}; soft gates are exact boolean logic, so the
// whole scan is: pack bits -> integer add -> unpack sum & carry bits.
//   S = X + Y;  sum bits = S[0:16];  carry[i] = (X^Y^S) >> (i+1).

#define BATCH 2097152
#define NB 16

__global__ __launch_bounds__(256) void rca_kernel(
    const uint4* __restrict__ x,   // (BATCH, 16) floats viewed as uint4 (4 per row)
    const uint4* __restrict__ y,
    float4* __restrict__ out)      // sum (BATCH,16) then carry (BATCH,16), as float4
{
    const int row = blockIdx.x * blockDim.x + threadIdx.x;
    if (row >= BATCH) return;

    const uint4* xp = x + (size_t)row * 4;
    const uint4* yp = y + (size_t)row * 4;

    unsigned int X = 0, Y = 0;
#pragma unroll
    for (int q = 0; q < 4; ++q) {
        uint4 xv = xp[q];
        uint4 yv = yp[q];
        // float 1.0f = 0x3F800000 -> exponent LSB (bit 23) == 1; 0.0f -> 0.
        X |= ((xv.x >> 23) & 1u) << (4 * q + 0);
        X |= ((xv.y >> 23) & 1u) << (4 * q + 1);
        X |= ((xv.z >> 23) & 1u) << (4 * q + 2);
        X |= ((xv.w >> 23) & 1u) << (4 * q + 3);
        Y |= ((yv.x >> 23) & 1u) << (4 * q + 0);
        Y |= ((yv.y >> 23) & 1u) << (4 * q + 1);
        Y |= ((yv.z >> 23) & 1u) << (4 * q + 2);
        Y |= ((yv.w >> 23) & 1u) << (4 * q + 3);
    }

    const unsigned int S = X + Y;              // 17-bit sum
    const unsigned int C = (X ^ Y ^ S) >> 1;   // carry-out per bit position

    float4* os = out + (size_t)row * 4;                       // sum output
    float4* oc = out + (size_t)BATCH * 4 + (size_t)row * 4;   // carry output

#pragma unroll
    for (int q = 0; q < 4; ++q) {
        float4 sv, cv;
        sv.x = (float)((S >> (4 * q + 0)) & 1u);
        sv.y = (float)((S >> (4 * q + 1)) & 1u);
        sv.z = (float)((S >> (4 * q + 2)) & 1u);
        sv.w = (float)((S >> (4 * q + 3)) & 1u);
        cv.x = (float)((C >> (4 * q + 0)) & 1u);
        cv.y = (float)((C >> (4 * q + 1)) & 1u);
        cv.z = (float)((C >> (4 * q + 2)) & 1u);
        cv.w = (float)((C >> (4 * q + 3)) & 1u);
        os[q] = sv;
        oc[q] = cv;
    }
}

extern "C" void kernel_launch(void* const* d_in, const int* in_sizes, int n_in,
                              void* d_out, int out_size, void* d_ws, size_t ws_size,
                              hipStream_t stream) {
    const uint4* x = (const uint4*)d_in[0];
    const uint4* y = (const uint4*)d_in[1];
    float4* out = (float4*)d_out;

    const int threads = 256;
    const int blocks = BATCH / threads;  // 2^21 / 256 = 8192
    rca_kernel<<<blocks, threads, 0, stream>>>(x, y, out);
}

// Round 2
// 427.566 us; speedup vs baseline: 1.0524x; 1.0524x over previous
//
#include <hip/hip_runtime.h>

// 16-bit ripple-carry adder over BATCH rows, fully-coalesced version.
//
// Inputs are float32 in {0,1}; the soft-gate scan is exact boolean logic:
//   S = X + Y;  sum bits = S[0:16];  carry[i] = ((X ^ Y ^ S) >> (i+1)) & 1.
//
// Layout trick: one thread per *nibble* (4 consecutive floats == 1 float4),
// so every global load/store is lane-contiguous 16 B (perfect coalescing).
// The 4 lanes of a row exchange nibbles via a 2-step __shfl_xor butterfly
// (X and Y packed into one 32-bit word -> 2 shuffles total), then each lane
// redundantly computes the full 16-bit add and writes back its own nibble.

#define BATCH 2097152
#define NB 16

__global__ __launch_bounds__(256) void rca_kernel(
    const uint4* __restrict__ x,   // BATCH*4 float4s, viewed as uint4
    const uint4* __restrict__ y,
    float4* __restrict__ out)      // sum (BATCH*4 float4s) then carry (BATCH*4)
{
    const unsigned int t = blockIdx.x * blockDim.x + threadIdx.x; // float4 index
    const int q = (int)(t & 3);                                   // nibble index in row

    const uint4 xv = x[t];
    const uint4 yv = y[t];

    // float 1.0f = 0x3F800000 -> bit 23 set; 0.0f -> 0.
    unsigned int nx = ((xv.x >> 23) & 1u)
                    | (((xv.y >> 23) & 1u) << 1)
                    | (((xv.z >> 23) & 1u) << 2)
                    | (((xv.w >> 23) & 1u) << 3);
    unsigned int ny = ((yv.x >> 23) & 1u)
                    | (((yv.y >> 23) & 1u) << 1)
                    | (((yv.z >> 23) & 1u) << 2)
                    | (((yv.w >> 23) & 1u) << 3);

    // Pack X nibble in bits [4q,4q+3], Y nibble in bits [16+4q,16+4q+3].
    unsigned int P = (nx << (4 * q)) | (ny << (4 * q + 16));
    // Butterfly-OR across the 4 lanes of this row (lanes differ in bits 0..1).
    P |= __shfl_xor((int)P, 1);
    P |= __shfl_xor((int)P, 2);

    const unsigned int X = P & 0xFFFFu;
    const unsigned int Y = P >> 16;
    const unsigned int S = X + Y;              // 17-bit sum
    const unsigned int C = (X ^ Y ^ S) >> 1;   // carry-out of each bit position

    const unsigned int s4 = (S >> (4 * q)) & 0xFu;
    const unsigned int c4 = (C >> (4 * q)) & 0xFu;

    float4 sv, cv;
    sv.x = (float)(s4 & 1u);
    sv.y = (float)((s4 >> 1) & 1u);
    sv.z = (float)((s4 >> 2) & 1u);
    sv.w = (float)((s4 >> 3) & 1u);
    cv.x = (float)(c4 & 1u);
    cv.y = (float)((c4 >> 1) & 1u);
    cv.z = (float)((c4 >> 2) & 1u);
    cv.w = (float)((c4 >> 3) & 1u);

    out[t] = sv;                              // sum block
    out[t + (size_t)BATCH * 4] = cv;          // carry block
}

extern "C" void kernel_launch(void* const* d_in, const int* in_sizes, int n_in,
                              void* d_out, int out_size, void* d_ws, size_t ws_size,
                              hipStream_t stream) {
    const uint4* x = (const uint4*)d_in[0];
    const uint4* y = (const uint4*)d_in[1];
    float4* out = (float4*)d_out;

    const int threads = 256;
    const int blocks = (BATCH * 4) / threads;  // 2^23 / 256 = 32768
    rca_kernel<<<blocks, threads, 0, stream>>>(x, y, out);
}

// Round 4
// 418.750 us; speedup vs baseline: 1.0745x; 1.0211x over previous
//
#include <hip/hip_runtime.h>

// 16-bit ripple-carry adder over BATCH rows, coalesced + non-temporal.
//
// Inputs are float32 in {0,1}; the soft-gate scan is exact boolean logic:
//   S = X + Y;  sum bits = S[0:16];  carry[i] = ((X ^ Y ^ S) >> (i+1)) & 1.
//
// One thread per nibble (4 consecutive floats == 1 native 16B vector): every
// global load/store is lane-contiguous 16 B (perfect coalescing). The 4 lanes
// of a row exchange nibbles via a 2-step __shfl_xor butterfly (X and Y packed
// in one 32-bit word -> 2 shuffles), then each lane redundantly computes the
// full 16-bit add and writes back its own nibble.
//
// All global accesses are non-temporal (zero reuse; keep streams out of
// L2/LLC). Native clang ext_vector types are used because
// __builtin_nontemporal_* rejects HIP_vector_type wrappers.

#define BATCH 2097152
#define NB 16

typedef unsigned int uintv4 __attribute__((ext_vector_type(4)));
typedef float floatv4 __attribute__((ext_vector_type(4)));

__global__ __launch_bounds__(256) void rca_kernel(
    const uintv4* __restrict__ x,   // BATCH*4 16B vectors
    const uintv4* __restrict__ y,
    floatv4* __restrict__ out)      // sum (BATCH*4 vecs) then carry (BATCH*4)
{
    const unsigned int t = blockIdx.x * blockDim.x + threadIdx.x; // vec4 index
    const int q = (int)(t & 3);                                   // nibble index in row

    const uintv4 xv = __builtin_nontemporal_load(&x[t]);
    const uintv4 yv = __builtin_nontemporal_load(&y[t]);

    // float 1.0f = 0x3F800000 -> bit 23 set; 0.0f -> 0.
    unsigned int nx = ((xv.x >> 23) & 1u)
                    | (((xv.y >> 23) & 1u) << 1)
                    | (((xv.z >> 23) & 1u) << 2)
                    | (((xv.w >> 23) & 1u) << 3);
    unsigned int ny = ((yv.x >> 23) & 1u)
                    | (((yv.y >> 23) & 1u) << 1)
                    | (((yv.z >> 23) & 1u) << 2)
                    | (((yv.w >> 23) & 1u) << 3);

    // Pack X nibble in bits [4q,4q+3], Y nibble in bits [16+4q,16+4q+3].
    unsigned int P = (nx << (4 * q)) | (ny << (4 * q + 16));
    // Butterfly-OR across the 4 lanes of this row (lanes differ in bits 0..1).
    P |= __shfl_xor((int)P, 1);
    P |= __shfl_xor((int)P, 2);

    const unsigned int X = P & 0xFFFFu;
    const unsigned int Y = P >> 16;
    const unsigned int S = X + Y;              // 17-bit sum
    const unsigned int C = (X ^ Y ^ S) >> 1;   // carry-out of each bit position

    const unsigned int s4 = (S >> (4 * q)) & 0xFu;
    const unsigned int c4 = (C >> (4 * q)) & 0xFu;

    floatv4 sv, cv;
    sv.x = (float)(s4 & 1u);
    sv.y = (float)((s4 >> 1) & 1u);
    sv.z = (float)((s4 >> 2) & 1u);
    sv.w = (float)((s4 >> 3) & 1u);
    cv.x = (float)(c4 & 1u);
    cv.y = (float)((c4 >> 1) & 1u);
    cv.z = (float)((c4 >> 2) & 1u);
    cv.w = (float)((c4 >> 3) & 1u);

    __builtin_nontemporal_store(sv, &out[t]);                        // sum block
    __builtin_nontemporal_store(cv, &out[t + (size_t)BATCH * 4]);    // carry block
}

extern "C" void kernel_launch(void* const* d_in, const int* in_sizes, int n_in,
                              void* d_out, int out_size, void* d_ws, size_t ws_size,
                              hipStream_t stream) {
    const uintv4* x = (const uintv4*)d_in[0];
    const uintv4* y = (const uintv4*)d_in[1];
    floatv4* out = (floatv4*)d_out;

    const int threads = 256;
    const int blocks = (BATCH * 4) / threads;  // 2^23 / 256 = 32768
    rca_kernel<<<blocks, threads, 0, stream>>>(x, y, out);
}